// Round 3
// baseline (282.938 us; speedup 1.0000x reference)
//
#include <hip/hip_runtime.h>

typedef __bf16 bf16;
typedef __bf16 bf16x8 __attribute__((ext_vector_type(8)));
typedef __bf16 bf16x4 __attribute__((ext_vector_type(4)));
typedef float f32x4 __attribute__((ext_vector_type(4)));

#define BS 4
#define SEQ 2048
#define DM 1024
#define NH 16
#define DKH 64

__device__ __forceinline__ void gload_lds16(const void* g, void* l) {
  __builtin_amdgcn_global_load_lds(
      (const __attribute__((address_space(1))) unsigned int*)g,
      (__attribute__((address_space(3))) unsigned int*)l, 16, 0, 0);
}

// ---------------------------------------------------------------------------
// W f32 -> bf16 (1M elems, done once; W reused by all proj blocks)
// ---------------------------------------------------------------------------
__global__ __launch_bounds__(256) void wconv(const float* __restrict__ W,
                                             bf16* __restrict__ Wb) {
  const int i = (blockIdx.x * 256 + threadIdx.x) * 4;
  f32x4 v = *(const f32x4*)(W + i);
  bf16x4 h;
#pragma unroll
  for (int j = 0; j < 4; ++j) h[j] = (bf16)v[j];
  *(bf16x4*)(Wb + i) = h;
}

// ---------------------------------------------------------------------------
// Projection: Y[m][n] = scale * sum_k X[m][k] * W[n][k]   (C = X @ W^T)
// Unchanged from round 2 (T2 on 2-phase is a measured NULL; 8-phase port is
// a future round). 128x128 tile, BK=64, 4 waves. grid = (8, 64, 3).
// ---------------------------------------------------------------------------
__global__ __launch_bounds__(256) void proj_gemm(
    const float* __restrict__ Qin, const float* __restrict__ Kin,
    const float* __restrict__ Vin, const bf16* __restrict__ Wb,
    bf16* __restrict__ qw, bf16* __restrict__ kw, bf16* __restrict__ vw) {
  __shared__ bf16 As[128 * 64];
  __shared__ bf16 Bs[128 * 64];
  const int z = blockIdx.z;
  const float* X = (z == 0) ? Qin : (z == 1) ? Kin : Vin;
  bf16* Y = (z == 0) ? qw : (z == 1) ? kw : vw;
  const float scale = (z == 0) ? 0.03125f : 1.0f;  // fold 1/sqrt(1024) into q

  const int tid = threadIdx.x;
  const int lane = tid & 63;
  const int w = tid >> 6;
  const int wm = w >> 1, wn = w & 1;
  const int m0 = blockIdx.y * 128;
  const int n0 = blockIdx.x * 128;
  const int lr = lane & 15;
  const int lg = lane >> 4;
  const int srow = tid >> 3;
  const int sc8 = (tid & 7) * 8;
  const int scolb = (tid & 7) * 16;

  f32x4 acc[4][4];
#pragma unroll
  for (int m = 0; m < 4; ++m)
#pragma unroll
    for (int n = 0; n < 4; ++n) acc[m][n] = (f32x4){0.f, 0.f, 0.f, 0.f};

  for (int k0 = 0; k0 < DM; k0 += 64) {
    __syncthreads();
#pragma unroll
    for (int q = 0; q < 4; ++q) {
      const float* src = X + (size_t)(m0 + q * 32 + srow) * DM + k0 + sc8;
      f32x4 f0 = *(const f32x4*)src;
      f32x4 f1 = *(const f32x4*)(src + 4);
      bf16x8 h;
#pragma unroll
      for (int i = 0; i < 4; ++i) { h[i] = (bf16)f0[i]; h[4 + i] = (bf16)f1[i]; }
      *(bf16x8*)(As + (q * 32 + srow) * 64 + sc8) = h;
    }
#pragma unroll
    for (int q = 0; q < 4; ++q)
      gload_lds16((const char*)(Wb + (size_t)(n0 + q * 32 + srow) * DM + k0) + scolb,
                  (char*)Bs + q * 4096 + tid * 16);
    __syncthreads();

#pragma unroll
    for (int kk = 0; kk < 2; ++kk) {
      bf16x8 af[4], bfr[4];
#pragma unroll
      for (int m = 0; m < 4; ++m)
        af[m] = *(const bf16x8*)(As + (wm * 64 + m * 16 + lr) * 64 + kk * 32 + lg * 8);
#pragma unroll
      for (int n = 0; n < 4; ++n)
        bfr[n] = *(const bf16x8*)(Bs + (wn * 64 + n * 16 + lr) * 64 + kk * 32 + lg * 8);
#pragma unroll
      for (int m = 0; m < 4; ++m)
#pragma unroll
        for (int n = 0; n < 4; ++n)
          acc[m][n] = __builtin_amdgcn_mfma_f32_16x16x32_bf16(af[m], bfr[n], acc[m][n], 0, 0, 0);
    }
  }

#pragma unroll
  for (int m = 0; m < 4; ++m)
#pragma unroll
    for (int n = 0; n < 4; ++n)
#pragma unroll
      for (int j = 0; j < 4; ++j) {
        const int row = m0 + wm * 64 + m * 16 + lg * 4 + j;
        const int col = n0 + wn * 64 + n * 16 + lr;
        Y[(size_t)row * DM + col] = (bf16)(acc[m][n][j] * scale);
      }
}

// ---------------------------------------------------------------------------
// V transpose: vw[b][seq][h*64+dk] -> vt[((b*16+h)*64+dk)][seq]  (unchanged)
// ---------------------------------------------------------------------------
__global__ __launch_bounds__(256) void vtrans(const bf16* __restrict__ v,
                                              bf16* __restrict__ vt) {
  __shared__ bf16 t[64][72];
  const int b = blockIdx.z, h = blockIdx.y, s0 = blockIdx.x * 64;
  const int tid = threadIdx.x;
#pragma unroll
  for (int p = 0; p < 2; ++p) {
    const int row = p * 32 + (tid >> 3);
    const int c = (tid & 7) * 8;
    bf16x8 d = *(const bf16x8*)(v + ((size_t)b * SEQ + s0 + row) * DM + h * 64 + c);
#pragma unroll
    for (int i = 0; i < 8; ++i) t[row][c + i] = d[i];
  }
  __syncthreads();
#pragma unroll
  for (int p = 0; p < 2; ++p) {
    const int dk = p * 32 + (tid >> 3);
    const int c = (tid & 7) * 8;
    union { bf16x8 v8; bf16 a[8]; } u;
#pragma unroll
    for (int i = 0; i < 8; ++i) u.a[i] = t[c + i][dk];
    *(bf16x8*)(vt + ((size_t)(b * NH + h) * DKH + dk) * SEQ + s0 + c) = u.v8;
  }
}

// ---------------------------------------------------------------------------
// Flash attention — ROUND 3: double-buffered K/V staging (stage(t+1) issued
// BEFORE compute(t); ONE barrier per tile so the vmcnt(0) drain lands after
// compute), T2 XOR-swizzle on ks/vs (pre-swizzled global source per rule 21)
// and ps (swizzled write+read), grid flattened 1D with b fastest.
// grid = 2048x1, block = 256 (4 waves x 16 q-rows). LDS = 40 KB (4 blk/CU).
// ---------------------------------------------------------------------------
__global__ __launch_bounds__(256) void attn_fwd(
    const bf16* __restrict__ qw, const bf16* __restrict__ kw,
    const bf16* __restrict__ vt, const int* __restrict__ lens,
    float* __restrict__ out) {
  __shared__ bf16 ks[2][64 * 64];
  __shared__ bf16 vs[2][64 * 64];
  __shared__ bf16 ps[4][16 * 64];
  const int idx = blockIdx.x;
  const int b = idx & 3, h = (idx >> 2) & 15, q0 = (idx >> 6) * 64;
  const int tid = threadIdx.x, lane = tid & 63, w = tid >> 6;
  const int lr = lane & 15, lg = lane >> 4;
  const int rsw = (lr & 7) << 4;  // read-side XOR (rows indexed by *+lr)
  const int len = lens[b];
  const int ntiles = (len + 63) >> 6;

  const int srow = tid >> 3;
  // staging: linear LDS dest (gload_lds requirement), INVERSE-swizzled global
  // source column so that swizzled reads see linear data (rule 21 / m173).
  const int scolb = ((tid & 7) * 16) ^ ((srow & 7) << 4);

  const bf16* kbase = kw + (size_t)b * SEQ * DM + h * 64;
  const bf16* vbase = vt + (size_t)(b * NH + h) * DKH * SEQ;

  auto stage = [&](int buf, int t) {
    const int k0 = t * 64;
#pragma unroll
    for (int q = 0; q < 2; ++q)
      gload_lds16((const char*)(kbase + (size_t)(k0 + q * 32 + srow) * DM) + scolb,
                  (char*)ks[buf] + q * 4096 + tid * 16);
#pragma unroll
    for (int q = 0; q < 2; ++q)
      gload_lds16((const char*)(vbase + (size_t)(q * 32 + srow) * SEQ + k0) + scolb,
                  (char*)vs[buf] + q * 4096 + tid * 16);
  };

  stage(0, 0);  // prologue: tile 0 in flight while we fetch Q

  const bf16* qbase = qw + ((size_t)b * SEQ + q0 + w * 16 + lr) * DM + h * 64 + lg * 8;
  const bf16x8 aq0 = *(const bf16x8*)(qbase);
  const bf16x8 aq1 = *(const bf16x8*)(qbase + 32);

  f32x4 acc[4];
#pragma unroll
  for (int n = 0; n < 4; ++n) acc[n] = (f32x4){0.f, 0.f, 0.f, 0.f};
  float mrow[4] = {-1e30f, -1e30f, -1e30f, -1e30f};
  float lrow[4] = {0.f, 0.f, 0.f, 0.f};

  __syncthreads();  // vmcnt(0) drained by compiler -> buf 0 readable

  int cur = 0;
  for (int t = 0; t < ntiles; ++t) {
    if (t + 1 < ntiles) stage(cur ^ 1, t + 1);  // overlap next-tile HBM/L2 latency

    // ---- S = q @ k^T (16 q-rows x 64 keys per wave) ----
    f32x4 s[4];
#pragma unroll
    for (int n = 0; n < 4; ++n) s[n] = (f32x4){0.f, 0.f, 0.f, 0.f};
#pragma unroll
    for (int kk = 0; kk < 2; ++kk) {
      const bf16x8 aqk = kk ? aq1 : aq0;
#pragma unroll
      for (int n = 0; n < 4; ++n) {
        bf16x8 bk = *(const bf16x8*)((const char*)ks[cur] + (n * 16 + lr) * 128 +
                                     ((kk * 64 + lg * 16) ^ rsw));
        s[n] = __builtin_amdgcn_mfma_f32_16x16x32_bf16(aqk, bk, s[n], 0, 0, 0);
      }
    }
    // mask keys >= len (only final partial tile)
    const int k0 = t * 64;
    if (k0 + 64 > len) {
#pragma unroll
      for (int n = 0; n < 4; ++n)
        if (k0 + n * 16 + lr >= len) {
          s[n][0] = -1e30f; s[n][1] = -1e30f; s[n][2] = -1e30f; s[n][3] = -1e30f;
        }
    }
    // ---- online softmax: row r = lg*4+j lives in 16 lanes with same lg ----
    float pmax[4];
#pragma unroll
    for (int j = 0; j < 4; ++j)
      pmax[j] = fmaxf(fmaxf(s[0][j], s[1][j]), fmaxf(s[2][j], s[3][j]));
#pragma unroll
    for (int d = 1; d < 16; d <<= 1)
#pragma unroll
      for (int j = 0; j < 4; ++j)
        pmax[j] = fmaxf(pmax[j], __shfl_xor(pmax[j], d, 64));
    float psum[4] = {0.f, 0.f, 0.f, 0.f};
#pragma unroll
    for (int j = 0; j < 4; ++j) {
      const float mn = fmaxf(mrow[j], pmax[j]);
      const float scl = __expf(mrow[j] - mn);
      mrow[j] = mn;
      lrow[j] *= scl;
#pragma unroll
      for (int n = 0; n < 4; ++n) acc[n][j] *= scl;
    }
#pragma unroll
    for (int n = 0; n < 4; ++n)
#pragma unroll
      for (int j = 0; j < 4; ++j) {
        const float p = __expf(s[n][j] - mrow[j]);
        psum[j] += p;
        const int row = lg * 4 + j;
        *(bf16*)((char*)ps[w] + row * 128 + (((n * 16 + lr) * 2) ^ ((row & 7) << 4))) = (bf16)p;
      }
#pragma unroll
    for (int d = 1; d < 16; d <<= 1)
#pragma unroll
      for (int j = 0; j < 4; ++j)
        psum[j] += __shfl_xor(psum[j], d, 64);
#pragma unroll
    for (int j = 0; j < 4; ++j) lrow[j] += psum[j];

    // ---- O += P @ V (wave-local ps; same-wave write->read ordering) ----
#pragma unroll
    for (int kk = 0; kk < 2; ++kk) {
      bf16x8 ap = *(const bf16x8*)((const char*)ps[w] + lr * 128 + ((kk * 64 + lg * 16) ^ rsw));
#pragma unroll
      for (int n = 0; n < 4; ++n) {
        bf16x8 bv = *(const bf16x8*)((const char*)vs[cur] + (n * 16 + lr) * 128 +
                                     ((kk * 64 + lg * 16) ^ rsw));
        acc[n] = __builtin_amdgcn_mfma_f32_16x16x32_bf16(ap, bv, acc[n], 0, 0, 0);
      }
    }

    if (t + 1 < ntiles) {
      __syncthreads();  // reads of buf cur done everywhere; stage of cur^1 drained
      cur ^= 1;
    }
  }

#pragma unroll
  for (int n = 0; n < 4; ++n)
#pragma unroll
    for (int j = 0; j < 4; ++j) {
      const int row = q0 + w * 16 + lg * 4 + j;
      const int col = h * 64 + n * 16 + lr;
      out[((size_t)b * SEQ + row) * DM + col] = acc[n][j] / lrow[j];
    }
}

extern "C" void kernel_launch(void* const* d_in, const int* in_sizes, int n_in,
                              void* d_out, int out_size, void* d_ws, size_t ws_size,
                              hipStream_t stream) {
  const float* Q = (const float*)d_in[0];
  const float* K = (const float*)d_in[1];
  const float* V = (const float*)d_in[2];
  const float* W = (const float*)d_in[3];
  const int* lens = (const int*)d_in[4];
  float* out = (float*)d_out;

  char* ws = (char*)d_ws;
  const size_t seg = (size_t)BS * SEQ * DM * sizeof(bf16);  // 16 MiB
  bf16* qw = (bf16*)(ws);
  bf16* kw = (bf16*)(ws + seg);
  bf16* vw = (bf16*)(ws + 2 * seg);
  bf16* vt = (bf16*)(ws + 3 * seg);
  bf16* Wb = (bf16*)(ws + 4 * seg);  // 2 MiB

  wconv<<<dim3((DM * DM) / (256 * 4)), 256, 0, stream>>>(W, Wb);
  proj_gemm<<<dim3(DM / 128, (BS * SEQ) / 128, 3), 256, 0, stream>>>(Q, K, V, Wb, qw, kw, vw);
  vtrans<<<dim3(SEQ / 64, NH, BS), 256, 0, stream>>>(vw, vt);
  attn_fwd<<<2048, 256, 0, stream>>>(qw, kw, vt, lens, out);
}

// Round 4
// 268.336 us; speedup vs baseline: 1.0544x; 1.0544x over previous
//
#include <hip/hip_runtime.h>

typedef __bf16 bf16;
typedef __bf16 bf16x8 __attribute__((ext_vector_type(8)));
typedef __bf16 bf16x4 __attribute__((ext_vector_type(4)));
typedef float f32x4 __attribute__((ext_vector_type(4)));

#define BS 4
#define SEQ 2048
#define DM 1024
#define NH 16
#define DKH 64
#define NITEMS 2048  // 4 b * 16 h * 32 q-blocks

__device__ __forceinline__ void gload_lds16(const void* g, void* l) {
  __builtin_amdgcn_global_load_lds(
      (const __attribute__((address_space(1))) unsigned int*)g,
      (__attribute__((address_space(3))) unsigned int*)l, 16, 0, 0);
}

// ---------------------------------------------------------------------------
// W f32 -> bf16; block 0 also builds the LPT batch permutation (len desc)
// and zeroes the work-queue ticket counter (runs first on every replay).
// ---------------------------------------------------------------------------
__global__ __launch_bounds__(256) void wconv(const float* __restrict__ W,
                                             bf16* __restrict__ Wb,
                                             const int* __restrict__ lens,
                                             int* __restrict__ perm,
                                             int* __restrict__ ctr) {
  const int i = (blockIdx.x * 256 + threadIdx.x) * 4;
  f32x4 v = *(const f32x4*)(W + i);
  bf16x4 h;
#pragma unroll
  for (int j = 0; j < 4; ++j) h[j] = (bf16)v[j];
  *(bf16x4*)(Wb + i) = h;
  if (blockIdx.x == 0 && threadIdx.x == 0) {
    int p[4] = {0, 1, 2, 3};
    int l[4] = {lens[0], lens[1], lens[2], lens[3]};
#pragma unroll
    for (int a = 0; a < 3; ++a)
#pragma unroll
      for (int c = 0; c < 3 - a; ++c)
        if (l[p[c + 1]] > l[p[c]]) { int tmp = p[c]; p[c] = p[c + 1]; p[c + 1] = tmp; }
#pragma unroll
    for (int a = 0; a < 4; ++a) perm[a] = p[a];
    *ctr = 0;
  }
}

// ---------------------------------------------------------------------------
// Projection: Y = scale * (X @ W^T). Unchanged (next round's target).
// ---------------------------------------------------------------------------
__global__ __launch_bounds__(256) void proj_gemm(
    const float* __restrict__ Qin, const float* __restrict__ Kin,
    const float* __restrict__ Vin, const bf16* __restrict__ Wb,
    bf16* __restrict__ qw, bf16* __restrict__ kw, bf16* __restrict__ vw) {
  __shared__ bf16 As[128 * 64];
  __shared__ bf16 Bs[128 * 64];
  const int z = blockIdx.z;
  const float* X = (z == 0) ? Qin : (z == 1) ? Kin : Vin;
  bf16* Y = (z == 0) ? qw : (z == 1) ? kw : vw;
  const float scale = (z == 0) ? 0.03125f : 1.0f;

  const int tid = threadIdx.x;
  const int lane = tid & 63;
  const int w = tid >> 6;
  const int wm = w >> 1, wn = w & 1;
  const int m0 = blockIdx.y * 128;
  const int n0 = blockIdx.x * 128;
  const int lr = lane & 15;
  const int lg = lane >> 4;
  const int srow = tid >> 3;
  const int sc8 = (tid & 7) * 8;
  const int scolb = (tid & 7) * 16;

  f32x4 acc[4][4];
#pragma unroll
  for (int m = 0; m < 4; ++m)
#pragma unroll
    for (int n = 0; n < 4; ++n) acc[m][n] = (f32x4){0.f, 0.f, 0.f, 0.f};

  for (int k0 = 0; k0 < DM; k0 += 64) {
    __syncthreads();
#pragma unroll
    for (int q = 0; q < 4; ++q) {
      const float* src = X + (size_t)(m0 + q * 32 + srow) * DM + k0 + sc8;
      f32x4 f0 = *(const f32x4*)src;
      f32x4 f1 = *(const f32x4*)(src + 4);
      bf16x8 h;
#pragma unroll
      for (int i = 0; i < 4; ++i) { h[i] = (bf16)f0[i]; h[4 + i] = (bf16)f1[i]; }
      *(bf16x8*)(As + (q * 32 + srow) * 64 + sc8) = h;
    }
#pragma unroll
    for (int q = 0; q < 4; ++q)
      gload_lds16((const char*)(Wb + (size_t)(n0 + q * 32 + srow) * DM + k0) + scolb,
                  (char*)Bs + q * 4096 + tid * 16);
    __syncthreads();

#pragma unroll
    for (int kk = 0; kk < 2; ++kk) {
      bf16x8 af[4], bfr[4];
#pragma unroll
      for (int m = 0; m < 4; ++m)
        af[m] = *(const bf16x8*)(As + (wm * 64 + m * 16 + lr) * 64 + kk * 32 + lg * 8);
#pragma unroll
      for (int n = 0; n < 4; ++n)
        bfr[n] = *(const bf16x8*)(Bs + (wn * 64 + n * 16 + lr) * 64 + kk * 32 + lg * 8);
#pragma unroll
      for (int m = 0; m < 4; ++m)
#pragma unroll
        for (int n = 0; n < 4; ++n)
          acc[m][n] = __builtin_amdgcn_mfma_f32_16x16x32_bf16(af[m], bfr[n], acc[m][n], 0, 0, 0);
    }
  }

#pragma unroll
  for (int m = 0; m < 4; ++m)
#pragma unroll
    for (int n = 0; n < 4; ++n)
#pragma unroll
      for (int j = 0; j < 4; ++j) {
        const int row = m0 + wm * 64 + m * 16 + lg * 4 + j;
        const int col = n0 + wn * 64 + n * 16 + lr;
        Y[(size_t)row * DM + col] = (bf16)(acc[m][n][j] * scale);
      }
}

// ---------------------------------------------------------------------------
// V transpose (unchanged).
// ---------------------------------------------------------------------------
__global__ __launch_bounds__(256) void vtrans(const bf16* __restrict__ v,
                                              bf16* __restrict__ vt) {
  __shared__ bf16 t[64][72];
  const int b = blockIdx.z, h = blockIdx.y, s0 = blockIdx.x * 64;
  const int tid = threadIdx.x;
#pragma unroll
  for (int p = 0; p < 2; ++p) {
    const int row = p * 32 + (tid >> 3);
    const int c = (tid & 7) * 8;
    bf16x8 d = *(const bf16x8*)(v + ((size_t)b * SEQ + s0 + row) * DM + h * 64 + c);
#pragma unroll
    for (int i = 0; i < 8; ++i) t[row][c + i] = d[i];
  }
  __syncthreads();
#pragma unroll
  for (int p = 0; p < 2; ++p) {
    const int dk = p * 32 + (tid >> 3);
    const int c = (tid & 7) * 8;
    union { bf16x8 v8; bf16 a[8]; } u;
#pragma unroll
    for (int i = 0; i < 8; ++i) u.a[i] = t[c + i][dk];
    *(bf16x8*)(vt + ((size_t)(b * NH + h) * DKH + dk) * SEQ + s0 + c) = u.v8;
  }
}

// ---------------------------------------------------------------------------
// Flash attention — ROUND 4: persistent blocks + atomic work queue (LPT
// ordered: longest batches first -> short tail), single-buffer K/V (24 KB
// LDS -> 6 blocks/CU, launch_bounds(256,6) -> 75% occupancy cap), psum via
// ones-column MFMA (kills the 4-step shfl reduce per tile).
// grid = 1536 persistent blocks, block = 256 (4 waves x 16 q-rows).
// ---------------------------------------------------------------------------
__global__ __launch_bounds__(256, 6) void attn_fwd(
    const bf16* __restrict__ qw, const bf16* __restrict__ kw,
    const bf16* __restrict__ vt, const int* __restrict__ lens,
    const int* __restrict__ perm, int* __restrict__ ctr,
    float* __restrict__ out) {
  __shared__ bf16 ks[64 * 64];
  __shared__ bf16 vs[64 * 64];
  __shared__ bf16 ps[4][16 * 64];
  __shared__ int s_item;
  const int tid = threadIdx.x, lane = tid & 63, w = tid >> 6;
  const int lr = lane & 15, lg = lane >> 4;
  const int rsw = (lr & 7) << 4;  // read-side XOR swizzle
  const int srow = tid >> 3;
  const int scolb = ((tid & 7) * 16) ^ ((srow & 7) << 4);  // inverse-swz source col

  // ones-column B-fragment: B[k][col] = (col==0) -> D[:,0] = row sums of A
  bf16x8 bones;
#pragma unroll
  for (int i = 0; i < 8; ++i) bones[i] = (lr == 0) ? (bf16)1.0f : (bf16)0.0f;

  for (;;) {
    __syncthreads();  // prior item's LDS reads done; s_item consumed
    if (tid == 0) s_item = atomicAdd(ctr, 1);
    __syncthreads();
    const int item = s_item;
    if (item >= NITEMS) return;

    const int b = perm[item >> 9];        // LPT: 512 items per batch, longest first
    const int h = (item >> 5) & 15;
    const int q0 = (item & 31) * 64;
    const int len = lens[b];
    const int ntiles = (len + 63) >> 6;

    const bf16* kbase = kw + (size_t)b * SEQ * DM + h * 64;
    const bf16* vbase = vt + (size_t)(b * NH + h) * DKH * SEQ;
    const bf16* qbase = qw + ((size_t)b * SEQ + q0 + w * 16 + lr) * DM + h * 64 + lg * 8;
    const bf16x8 aq0 = *(const bf16x8*)(qbase);
    const bf16x8 aq1 = *(const bf16x8*)(qbase + 32);

    f32x4 acc[4];
#pragma unroll
    for (int n = 0; n < 4; ++n) acc[n] = (f32x4){0.f, 0.f, 0.f, 0.f};
    f32x4 acc1 = (f32x4){0.f, 0.f, 0.f, 0.f};  // row-sum accumulator (col 0)
    float mrow[4] = {-1e30f, -1e30f, -1e30f, -1e30f};

    for (int t = 0; t < ntiles; ++t) {
      const int k0 = t * 64;
      __syncthreads();  // prior tile's ks/vs reads complete (lgkm drained)
#pragma unroll
      for (int q = 0; q < 2; ++q)
        gload_lds16((const char*)(kbase + (size_t)(k0 + q * 32 + srow) * DM) + scolb,
                    (char*)ks + q * 4096 + tid * 16);
#pragma unroll
      for (int q = 0; q < 2; ++q)
        gload_lds16((const char*)(vbase + (size_t)(q * 32 + srow) * SEQ + k0) + scolb,
                    (char*)vs + q * 4096 + tid * 16);
      __syncthreads();  // vmcnt drained -> tiles readable by all waves

      // ---- S = q @ k^T ----
      f32x4 s[4];
#pragma unroll
      for (int n = 0; n < 4; ++n) s[n] = (f32x4){0.f, 0.f, 0.f, 0.f};
#pragma unroll
      for (int kk = 0; kk < 2; ++kk) {
        const bf16x8 aqk = kk ? aq1 : aq0;
#pragma unroll
        for (int n = 0; n < 4; ++n) {
          bf16x8 bk = *(const bf16x8*)((const char*)ks + (n * 16 + lr) * 128 +
                                       ((kk * 64 + lg * 16) ^ rsw));
          s[n] = __builtin_amdgcn_mfma_f32_16x16x32_bf16(aqk, bk, s[n], 0, 0, 0);
        }
      }
      if (k0 + 64 > len) {  // mask keys >= len (final partial tile only)
#pragma unroll
        for (int n = 0; n < 4; ++n)
          if (k0 + n * 16 + lr >= len) {
            s[n][0] = -1e30f; s[n][1] = -1e30f; s[n][2] = -1e30f; s[n][3] = -1e30f;
          }
      }
      // ---- online softmax (row r = lg*4+j across the 16 lanes sharing lg) ----
      float pmax[4];
#pragma unroll
      for (int j = 0; j < 4; ++j)
        pmax[j] = fmaxf(fmaxf(s[0][j], s[1][j]), fmaxf(s[2][j], s[3][j]));
#pragma unroll
      for (int d = 1; d < 16; d <<= 1)
#pragma unroll
        for (int j = 0; j < 4; ++j)
          pmax[j] = fmaxf(pmax[j], __shfl_xor(pmax[j], d, 64));
#pragma unroll
      for (int j = 0; j < 4; ++j) {
        const float mn = fmaxf(mrow[j], pmax[j]);
        const float scl = __expf(mrow[j] - mn);
        mrow[j] = mn;
        acc1[j] *= scl;
#pragma unroll
        for (int n = 0; n < 4; ++n) acc[n][j] *= scl;
      }
#pragma unroll
      for (int n = 0; n < 4; ++n)
#pragma unroll
        for (int j = 0; j < 4; ++j) {
          const float p = __expf(s[n][j] - mrow[j]);
          const int row = lg * 4 + j;
          *(bf16*)((char*)ps[w] + row * 128 + (((n * 16 + lr) * 2) ^ ((row & 7) << 4))) = (bf16)p;
        }

      // ---- O += P @ V; row-sums += P @ ones (wave-local ps) ----
#pragma unroll
      for (int kk = 0; kk < 2; ++kk) {
        bf16x8 ap = *(const bf16x8*)((const char*)ps[w] + lr * 128 + ((kk * 64 + lg * 16) ^ rsw));
#pragma unroll
        for (int n = 0; n < 4; ++n) {
          bf16x8 bv = *(const bf16x8*)((const char*)vs + (n * 16 + lr) * 128 +
                                       ((kk * 64 + lg * 16) ^ rsw));
          acc[n] = __builtin_amdgcn_mfma_f32_16x16x32_bf16(ap, bv, acc[n], 0, 0, 0);
        }
        acc1 = __builtin_amdgcn_mfma_f32_16x16x32_bf16(ap, bones, acc1, 0, 0, 0);
      }
    }

    // lrow[j] lives in the lr==0 lane of each lg group -> broadcast
    float lrow[4];
#pragma unroll
    for (int j = 0; j < 4; ++j) lrow[j] = __shfl(acc1[j], lane & 48, 64);

#pragma unroll
    for (int n = 0; n < 4; ++n)
#pragma unroll
      for (int j = 0; j < 4; ++j) {
        const int row = q0 + w * 16 + lg * 4 + j;
        const int col = h * 64 + n * 16 + lr;
        out[((size_t)b * SEQ + row) * DM + col] = acc[n][j] / lrow[j];
      }
  }
}

extern "C" void kernel_launch(void* const* d_in, const int* in_sizes, int n_in,
                              void* d_out, int out_size, void* d_ws, size_t ws_size,
                              hipStream_t stream) {
  const float* Q = (const float*)d_in[0];
  const float* K = (const float*)d_in[1];
  const float* V = (const float*)d_in[2];
  const float* W = (const float*)d_in[3];
  const int* lens = (const int*)d_in[4];
  float* out = (float*)d_out;

  char* ws = (char*)d_ws;
  const size_t seg = (size_t)BS * SEQ * DM * sizeof(bf16);  // 16 MiB
  bf16* qw = (bf16*)(ws);
  bf16* kw = (bf16*)(ws + seg);
  bf16* vw = (bf16*)(ws + 2 * seg);
  bf16* vt = (bf16*)(ws + 3 * seg);
  bf16* Wb = (bf16*)(ws + 4 * seg);            // 2 MiB
  int* perm = (int*)(ws + 4 * seg + 0x200000);  // 16 B
  int* ctr = perm + 4;

  wconv<<<dim3((DM * DM) / (256 * 4)), 256, 0, stream>>>(W, Wb, lens, perm, ctr);
  proj_gemm<<<dim3(DM / 128, (BS * SEQ) / 128, 3), 256, 0, stream>>>(Q, K, V, Wb, qw, kw, vw);
  vtrans<<<dim3(SEQ / 64, NH, BS), 256, 0, stream>>>(vw, vt);
  attn_fwd<<<1536, 256, 0, stream>>>(qw, kw, vt, lens, perm, ctr, out);
}